// Round 3
// baseline (111.273 us; speedup 1.0000x reference)
//
#include <hip/hip_runtime.h>

namespace {

constexpr int kB = 8, kO = 128, kI = 128, kD = 1024;
constexpr long kOutAttnOff = (long)kB * kO * kD;   // 1,048,576 floats

typedef __attribute__((ext_vector_type(8))) short short8;  // 8 bf16 = 4 VGPR
typedef __attribute__((ext_vector_type(4))) float f32x4;
typedef __attribute__((ext_vector_type(2))) float f32x2;

__device__ __forceinline__ float leaky(float x) { return x > 0.0f ? x : 0.01f * x; }

// fp32 -> bf16 round-to-nearest-even
__device__ __forceinline__ short f2bf(float f) {
    unsigned u = __builtin_bit_cast(unsigned, f);
    u += 0x7FFFu + ((u >> 16) & 1u);
    return (short)(u >> 16);
}

// async global->LDS, 16B per lane. LDS dest = wave-uniform base + lane*16.
__device__ __forceinline__ void gll16(const short* g, short* l) {
    __builtin_amdgcn_global_load_lds(
        (const __attribute__((address_space(1))) short*)g,
        (__attribute__((address_space(3))) short*)l, 16, 0, 0);
}

// ---------------------------------------------------------------------------
// All input conversions in ONE kernel.
//   blocks [0,1024):  straight fp32->bf16 of output (512) then context (512)
//   blocks [1024,2304): 64x64 transpose+convert tiles:
//     w_out_w (256), w_ctx_w (256), lin_w (512), context batched (256)
// ---------------------------------------------------------------------------
__global__ __launch_bounds__(256)
void conv_all(const float* __restrict__ output, const float* __restrict__ context,
              const float* __restrict__ w1, const float* __restrict__ w2,
              const float* __restrict__ lin,
              short* __restrict__ ob16, short* __restrict__ cb16,
              short* __restrict__ w1t, short* __restrict__ w2t,
              short* __restrict__ lint, short* __restrict__ ctxt)
{
    __shared__ float T[64][68];
    const int bid = blockIdx.x, tid = threadIdx.x;

    if (bid < 1024) {                       // straight convert, 8 floats/thread
        const int idx = bid * 256 + tid;
        const float* src; short* dst; int i;
        if (idx < (1 << 17)) { src = output;  dst = ob16; i = idx; }
        else                 { src = context; dst = cb16; i = idx - (1 << 17); }
        const float4* s4 = (const float4*)src + (long)i * 2;
        const float4 v0 = s4[0], v1 = s4[1];
        short8 r;
        r[0] = f2bf(v0.x); r[1] = f2bf(v0.y); r[2] = f2bf(v0.z); r[3] = f2bf(v0.w);
        r[4] = f2bf(v1.x); r[5] = f2bf(v1.y); r[6] = f2bf(v1.z); r[7] = f2bf(v1.w);
        *(short8*)(dst + (long)i * 8) = r;
        return;
    }

    const int tb = bid - 1024;
    const float* src; short* dst; long C, R; int t2;
    if (tb < 256)       { src = w1;  dst = w1t;  R = 1024; C = 1024; t2 = tb; }
    else if (tb < 512)  { src = w2;  dst = w2t;  R = 1024; C = 1024; t2 = tb - 256; }
    else if (tb < 1024) { src = lin; dst = lint; R = 2048; C = 1024; t2 = tb - 512; }
    else {
        const int tt = tb - 1024; const int bz = tt >> 5; t2 = tt & 31;
        R = 128; C = 1024;
        src = context + (long)bz * 128 * 1024;
        dst = ctxt    + (long)bz * 1024 * 128;
    }
    const int tr = t2 >> 4, tc = t2 & 15;
    const int r = tid >> 2, q = tid & 3;

    const float* s = src + (long)(tr * 64 + r) * C + tc * 64 + q * 16;
    const float4 a0 = ((const float4*)s)[0];
    const float4 a1 = ((const float4*)s)[1];
    const float4 a2 = ((const float4*)s)[2];
    const float4 a3 = ((const float4*)s)[3];
    *(float4*)&T[r][q * 16 + 0]  = a0;
    *(float4*)&T[r][q * 16 + 4]  = a1;
    *(float4*)&T[r][q * 16 + 8]  = a2;
    *(float4*)&T[r][q * 16 + 12] = a3;
    __syncthreads();

    short8 o0, o1;
#pragma unroll
    for (int j = 0; j < 8; ++j)  o0[j] = f2bf(T[q * 16 + j][r]);
#pragma unroll
    for (int j = 0; j < 8; ++j)  o1[j] = f2bf(T[q * 16 + 8 + j][r]);
    short* dp = dst + (long)(tc * 64 + r) * R + tr * 64 + q * 16;
    *(short8*)dp       = o0;
    *((short8*)dp + 1) = o1;
}

// ---------------------------------------------------------------------------
// bf16 MFMA GEMM, 64x64 tile, BK=64, 4 waves (wave = 32x32 via 2x2 of
// 16x16x32). Double-buffered LDS filled by global_load_lds (16B), 2-phase:
// stage(t+1) issued before compute(t); barrier drains vmcnt after compute.
// LDS is linear [64][64] bf16 (128B rows); bank-conflict-free via XOR chunk
// swizzle applied to BOTH the per-lane global source col and the ds_read col:
//   LDS[row][c16] = global[row][c16 ^ (row&7)].
// A is [M,K] bf16 (dual source along K: k<ksplit -> A1 else A2, same lda).
// Bt is B^T bf16 [N][K]. Batch strides sA/sB/sC by z. For the fused
// s_out/s_ctx launch, z==1's C comes from Cz1 and bias applies per bias_zmask.
// ---------------------------------------------------------------------------
template<bool BIAS, bool LEAKY, bool BF16OUT>
__global__ __launch_bounds__(256)
void gemm_mfma(const short* __restrict__ A1, const short* __restrict__ A2,
               int ksplit, int lda, const short* __restrict__ Bt, int ldb,
               const float* __restrict__ bias, int bias_zmask,
               void* __restrict__ Cout, void* __restrict__ Cz1,
               int ldc, int K, long sA, long sB, long sC)
{
    __shared__ short As[2][64][64];
    __shared__ short Bs[2][64][64];
    const int tid = threadIdx.x;
    const int bn = blockIdx.x * 64, bm = blockIdx.y * 64;
    const long z = blockIdx.z;
    const short* A1z = A1 + z * sA;
    const short* A2z = A2 + z * sA;
    const short* Btz = Bt + z * sB;

    const int lane = tid & 63, w = tid >> 6;
    const int w16 = w * 16;
    const int m0 = (w >> 1) * 32, n0 = (w & 1) * 32;
    const int fr = lane & 15;           // fragment row within 16
    const int fcol = lane >> 4;         // fragment col16 component (0..3)
    const int sl = lane & 7;            // row&7 of every frag row this lane reads
    const int r8 = lane >> 3;           // staging row within 8-row stripe
    const int sw8 = ((lane & 7) ^ ((lane >> 3) & 7)) * 8;  // swizzled src col (shorts)

    f32x4 acc00{}, acc01{}, acc10{}, acc11{};
    const int NS = K >> 6;

    auto stage = [&](int buf, int k0) {
        const short* ab; int ak;
        if (k0 < ksplit) { ab = A1z; ak = k0; }
        else             { ab = A2z; ak = k0 - ksplit; }
        const short* ga = ab + (long)(bm + w16 + r8) * lda + ak + sw8;
        gll16(ga,           &As[buf][w16][0]);
        gll16(ga + 8 * lda, &As[buf][w16 + 8][0]);
        const short* gb = Btz + (long)(bn + w16 + r8) * ldb + k0 + sw8;
        gll16(gb,           &Bs[buf][w16][0]);
        gll16(gb + 8 * ldb, &Bs[buf][w16 + 8][0]);
    };

    stage(0, 0);
    __syncthreads();
    int cur = 0;
    for (int s = 0; s < NS; ++s) {
        if (s + 1 < NS) stage(cur ^ 1, (s + 1) << 6);
#pragma unroll
        for (int ks8 = 0; ks8 < 8; ks8 += 4) {      // ks = 0, 32
            const int sa = ((ks8 + fcol) ^ sl) * 8; // swizzled read col (shorts)
            const short8 a0 = *(const short8*)&As[cur][m0 + fr][sa];
            const short8 a1 = *(const short8*)&As[cur][m0 + 16 + fr][sa];
            const short8 b0 = *(const short8*)&Bs[cur][n0 + fr][sa];
            const short8 b1 = *(const short8*)&Bs[cur][n0 + 16 + fr][sa];
            acc00 = __builtin_amdgcn_mfma_f32_16x16x32_bf16(a0, b0, acc00, 0, 0, 0);
            acc01 = __builtin_amdgcn_mfma_f32_16x16x32_bf16(a0, b1, acc01, 0, 0, 0);
            acc10 = __builtin_amdgcn_mfma_f32_16x16x32_bf16(a1, b0, acc10, 0, 0, 0);
            acc11 = __builtin_amdgcn_mfma_f32_16x16x32_bf16(a1, b1, acc11, 0, 0, 0);
        }
        __syncthreads();
        cur ^= 1;
    }

    const bool doBias = BIAS && ((bias_zmask >> z) & 1);
    float bv[2] = {0.0f, 0.0f};
    if (doBias) {
        bv[0] = bias[bn + n0 + fr];
        bv[1] = bias[bn + n0 + 16 + fr];
    }
    const f32x4 accs[2][2] = {{acc00, acc01}, {acc10, acc11}};
#pragma unroll
    for (int mi = 0; mi < 2; ++mi)
#pragma unroll
        for (int ni = 0; ni < 2; ++ni)
#pragma unroll
            for (int r = 0; r < 4; ++r) {
                const int row = bm + m0 + mi * 16 + ((lane >> 4) << 2) + r;
                const int col = bn + n0 + ni * 16 + fr;
                float v = accs[mi][ni][r];
                if (doBias) v += bv[ni];
                if (LEAKY)  v = leaky(v);
                if (BF16OUT) {
                    short* Ch = (short*)Cout + z * sC;
                    Ch[(long)row * ldc + col] = f2bf(v);
                } else {
                    float* Cf = (Cz1 != nullptr && z == 1)
                              ? (float*)Cz1 : ((float*)Cout + z * sC);
                    Cf[(long)row * ldc + col] = v;
                }
            }
}

// ---------------------------------------------------------------------------
// Fused score + mask + softmax. Block: (b, o-pair). 4 waves: wave w ->
// o-row (w>>1), i-half (w&1); one i per thread. 512 blocks = 2/CU.
// Inner product uses leaky(x) = 0.505x + 0.495|x| with two packed f32x2
// accumulators (v_pk_fma-friendly); constants folded after the loop.
// ---------------------------------------------------------------------------
__global__ __launch_bounds__(256)
void score_softmax3(const float* __restrict__ s_out, const float* __restrict__ s_ctx,
                    const float* __restrict__ score_w, const float* __restrict__ score_b,
                    const int* __restrict__ mask, float* __restrict__ attn_f32,
                    short* __restrict__ attn_b16)
{
    __shared__ float As[2][1032];
    __shared__ float Cs[128][68];
    __shared__ float Wsh[1024];
    __shared__ float Ssc[2][128];
    __shared__ int   Msk[128];

    const int b   = blockIdx.x;
    const int o0  = blockIdx.y * 2;
    const int tid = threadIdx.x;
    const int wv  = tid >> 6;
    const int ln  = tid & 63;
    const int ow  = wv >> 1;          // o-row within pair (wave-uniform)
    const int ih  = wv & 1;           // i-half
    const int i   = ih * 64 + ln;

    const float* arow = s_out + (long)(b * kO + o0) * kD;
#pragma unroll
    for (int q = 0; q < 2; ++q) {
        const int t  = tid + q * 256;
        const int rr = t >> 8;
        const int c4 = (t & 255) * 4;
        *(float4*)&As[rr][c4] = *(const float4*)&arow[(long)rr * kD + c4];
    }
    *(float4*)&Wsh[tid * 4] = *(const float4*)&score_w[tid * 4];
    if (tid < 128) Msk[tid] = mask[b * kI + tid];

    f32x2 accL{0.0f, 0.0f}, accA{0.0f, 0.0f};
    const float* crow = s_ctx + (long)b * kI * kD;

    for (int dc = 0; dc < kD; dc += 64) {
        __syncthreads();
#pragma unroll
        for (int q = 0; q < 8; ++q) {
            const int t  = tid + q * 256;
            const int rr = t >> 4;
            const int c4 = (t & 15) * 4;
            *(float4*)&Cs[rr][c4] = *(const float4*)&crow[(long)rr * kD + dc + c4];
        }
        __syncthreads();
#pragma unroll
        for (int kk = 0; kk < 64; kk += 4) {
            const float4 w4 = *(const float4*)&Wsh[dc + kk];
            const float4 av = *(const float4*)&As[ow][dc + kk];   // broadcast
            const float4 c0 = *(const float4*)&Cs[i][kk];
            const f32x2 x0 = {av.x + c0.x, av.y + c0.y};
            const f32x2 x1 = {av.z + c0.z, av.w + c0.w};
            const f32x2 w0 = {w4.x, w4.y};
            const f32x2 w1 = {w4.z, w4.w};
            const f32x2 ax0 = {__builtin_fabsf(x0.x), __builtin_fabsf(x0.y)};
            const f32x2 ax1 = {__builtin_fabsf(x1.x), __builtin_fabsf(x1.y)};
            accL += x0 * w0;
            accL += x1 * w1;
            accA += ax0 * w0;
            accA += ax1 * w1;
        }
    }

    const float negInf = -__builtin_huge_valf();
    float s = 0.505f * (accL.x + accL.y) + 0.495f * (accA.x + accA.y) + score_b[0];
    if (Msk[i] != 0) s = negInf;
    Ssc[ow][i] = s;
    __syncthreads();

    const float s0 = Ssc[ow][ln];
    const float s1 = Ssc[ow][ln + 64];
    float m = fmaxf(s0, s1);
#pragma unroll
    for (int d = 1; d < 64; d <<= 1) m = fmaxf(m, __shfl_xor(m, d, 64));
    const float e0 = __expf(s0 - m);
    const float e1 = __expf(s1 - m);
    float sum = e0 + e1;
#pragma unroll
    for (int d = 1; d < 64; d <<= 1) sum += __shfl_xor(sum, d, 64);
    const float inv = 1.0f / sum;

    if (ih == 0) {
        const long rowoff = (long)(b * kO + o0 + ow) * kI;
        float* ro = attn_f32 + rowoff;
        short* rh = attn_b16 + rowoff;
        const float p0 = e0 * inv, p1 = e1 * inv;
        ro[ln]      = p0;
        ro[ln + 64] = p1;
        rh[ln]      = f2bf(p0);
        rh[ln + 64] = f2bf(p1);
    }
}

} // namespace

extern "C" void kernel_launch(void* const* d_in, const int* in_sizes, int n_in,
                              void* d_out, int out_size, void* d_ws, size_t ws_size,
                              hipStream_t stream)
{
    const float* output  = (const float*)d_in[0];   // [B,O,D]
    const float* context = (const float*)d_in[1];   // [B,I,D]
    const int*   mask    = (const int*)d_in[2];     // [B,I]
    const float* w_out_w = (const float*)d_in[3];   // [D,D]
    const float* w_ctx_w = (const float*)d_in[4];   // [D,D]
    const float* w_b     = (const float*)d_in[5];   // [D]
    const float* score_w = (const float*)d_in[6];   // [D]
    const float* score_b = (const float*)d_in[7];   // scalar
    const float* lin_w   = (const float*)d_in[8];   // [2D,D]
    const float* lin_b   = (const float*)d_in[9];   // [D]

    float* out_main = (float*)d_out;                 // [B,O,D]
    float* out_attn = out_main + kOutAttnOff;        // [B,O,I]
    float* s_out    = out_main;                      // overlay: dead before step 5

    char* wp = (char*)d_ws;
    float* s_ctx = (float*)wp;  wp += (size_t)4 << 20;   // 4 MB fp32 [B*I][D]
    short* ob16  = (short*)wp;  wp += (size_t)2 << 20;   // output bf16
    short* cb16  = (short*)wp;  wp += (size_t)2 << 20;   // context bf16 (= ob16+1M)
    short* w1t   = (short*)wp;  wp += (size_t)2 << 20;   // w_out_w^T bf16 [N][K]
    short* w2t   = (short*)wp;  wp += (size_t)2 << 20;   // w_ctx_w^T (= w1t+1M)
    short* lint  = (short*)wp;  wp += (size_t)4 << 20;   // lin_w^T bf16 [1024][2048]
    short* ctxt  = (short*)wp;  wp += (size_t)2 << 20;   // context^T bf16 per-b [1024][128]
    short* attn16 = (short*)wp;                          // 256 KB bf16 attn
    short* t16 = (short*)s_ctx;                          // overlay: s_ctx dead after score

    const dim3 blk(256);

    // 0) all conversions (straight + transposes) in one launch
    hipLaunchKernelGGL(conv_all, dim3(2304), blk, 0, stream,
        output, context, w_out_w, w_ctx_w, lin_w,
        ob16, cb16, w1t, w2t, lint, ctxt);

    // 1+2) fused: z=0: s_out = output @ w_out_w + w_b ; z=1: s_ctx = context @ w_ctx_w
    hipLaunchKernelGGL((gemm_mfma<true, false, false>), dim3(16, 16, 2), blk, 0, stream,
        ob16, ob16, 1024, 1024, w1t, 1024, w_b, /*zmask*/1,
        (void*)s_out, (void*)s_ctx, 1024, 1024, (long)1 << 20, (long)1 << 20, 0L);

    // 3) attn = softmax(mask(leaky(s_out + s_ctx) . score_w + score_b))
    hipLaunchKernelGGL(score_softmax3, dim3(8, 64, 1), blk, 0, stream,
        s_out, s_ctx, score_w, score_b, mask, out_attn, attn16);

    // 4) t = attn @ context  (batched over b, bf16 out)
    hipLaunchKernelGGL((gemm_mfma<false, false, true>), dim3(16, 2, 8), blk, 0, stream,
        attn16, attn16, 128, 128, ctxt, 128, nullptr, 0,
        (void*)t16, nullptr, 1024, 128,
        (long)kO * kI, (long)kI * kD, (long)kO * kD);

    // 5) out = leaky([t | output] @ lin_w + lin_b)
    hipLaunchKernelGGL((gemm_mfma<true, true, false>), dim3(16, 16, 1), blk, 0, stream,
        t16, ob16, 1024, 1024, lint, 2048, lin_b, /*zmask*/1,
        (void*)out_main, nullptr, 1024, 2048, 0L, 0L, 0L);
}

// Round 4
// 78.227 us; speedup vs baseline: 1.4224x; 1.4224x over previous
//
#include <hip/hip_runtime.h>

namespace {

constexpr int kB = 8, kO = 128, kI = 128, kD = 1024;
constexpr long kOutAttnOff = (long)kB * kO * kD;   // 1,048,576 floats

typedef __attribute__((ext_vector_type(8))) short short8;  // 8 bf16 = 4 VGPR
typedef __attribute__((ext_vector_type(4))) float f32x4;

__device__ __forceinline__ float leaky(float x) { return fmaxf(x, 0.01f * x); }

// fp32 -> bf16 round-to-nearest-even
__device__ __forceinline__ short f2bf(float f) {
    unsigned u = __builtin_bit_cast(unsigned, f);
    u += 0x7FFFu + ((u >> 16) & 1u);
    return (short)(u >> 16);
}

// async global->LDS, 16B per lane. LDS dest = wave-uniform base + lane*16.
__device__ __forceinline__ void gll16(const short* g, short* l) {
    __builtin_amdgcn_global_load_lds(
        (const __attribute__((address_space(1))) short*)g,
        (__attribute__((address_space(3))) short*)l, 16, 0, 0);
}

// ---------------------------------------------------------------------------
// All input conversions in ONE kernel.
//   blocks [0,1024):  straight fp32->bf16 of output (512) then context (512)
//   blocks [1024,2304): 64x64 transpose+convert tiles:
//     w_out_w (256), w_ctx_w (256), lin_w (512), context batched (256)
// ---------------------------------------------------------------------------
__global__ __launch_bounds__(256)
void conv_all(const float* __restrict__ output, const float* __restrict__ context,
              const float* __restrict__ w1, const float* __restrict__ w2,
              const float* __restrict__ lin,
              short* __restrict__ ob16, short* __restrict__ cb16,
              short* __restrict__ w1t, short* __restrict__ w2t,
              short* __restrict__ lint, short* __restrict__ ctxt)
{
    __shared__ float T[64][68];
    const int bid = blockIdx.x, tid = threadIdx.x;

    if (bid < 1024) {                       // straight convert, 8 floats/thread
        const int idx = bid * 256 + tid;
        const float* src; short* dst; int i;
        if (idx < (1 << 17)) { src = output;  dst = ob16; i = idx; }
        else                 { src = context; dst = cb16; i = idx - (1 << 17); }
        const float4* s4 = (const float4*)src + (long)i * 2;
        const float4 v0 = s4[0], v1 = s4[1];
        short8 r;
        r[0] = f2bf(v0.x); r[1] = f2bf(v0.y); r[2] = f2bf(v0.z); r[3] = f2bf(v0.w);
        r[4] = f2bf(v1.x); r[5] = f2bf(v1.y); r[6] = f2bf(v1.z); r[7] = f2bf(v1.w);
        *(short8*)(dst + (long)i * 8) = r;
        return;
    }

    const int tb = bid - 1024;
    const float* src; short* dst; long C, R; int t2;
    if (tb < 256)       { src = w1;  dst = w1t;  R = 1024; C = 1024; t2 = tb; }
    else if (tb < 512)  { src = w2;  dst = w2t;  R = 1024; C = 1024; t2 = tb - 256; }
    else if (tb < 1024) { src = lin; dst = lint; R = 2048; C = 1024; t2 = tb - 512; }
    else {
        const int tt = tb - 1024; const int bz = tt >> 5; t2 = tt & 31;
        R = 128; C = 1024;
        src = context + (long)bz * 128 * 1024;
        dst = ctxt    + (long)bz * 1024 * 128;
    }
    const int tr = t2 >> 4, tc = t2 & 15;
    const int r = tid >> 2, q = tid & 3;

    const float* s = src + (long)(tr * 64 + r) * C + tc * 64 + q * 16;
    const float4 a0 = ((const float4*)s)[0];
    const float4 a1 = ((const float4*)s)[1];
    const float4 a2 = ((const float4*)s)[2];
    const float4 a3 = ((const float4*)s)[3];
    *(float4*)&T[r][q * 16 + 0]  = a0;
    *(float4*)&T[r][q * 16 + 4]  = a1;
    *(float4*)&T[r][q * 16 + 8]  = a2;
    *(float4*)&T[r][q * 16 + 12] = a3;
    __syncthreads();

    short8 o0, o1;
#pragma unroll
    for (int j = 0; j < 8; ++j)  o0[j] = f2bf(T[q * 16 + j][r]);
#pragma unroll
    for (int j = 0; j < 8; ++j)  o1[j] = f2bf(T[q * 16 + 8 + j][r]);
    short* dp = dst + (long)(tc * 64 + r) * R + tr * 64 + q * 16;
    *(short8*)dp       = o0;
    *((short8*)dp + 1) = o1;
}

// ---------------------------------------------------------------------------
// bf16 MFMA GEMM, 64x64 tile, BK=64, 4 waves (wave = 32x32 via 2x2 of
// 16x16x32). Double-buffered LDS filled by global_load_lds (16B), 2-phase.
// LDS linear [64][64] bf16; bank-conflict-free via XOR chunk swizzle applied
// to BOTH the per-lane global source col and the ds_read col (rule #21).
// A is [M,K] bf16 (dual source along K: k<ksplit -> A1 else A2, same lda).
// Bt is B^T bf16 [N][K]. Batch strides sA/sB/sC by z. For the fused
// s_out/s_ctx launch, z==1's C goes to Cz1 and bias applies per bias_zmask.
// ---------------------------------------------------------------------------
template<bool BIAS, bool LEAKY, bool BF16OUT>
__global__ __launch_bounds__(256)
void gemm_mfma(const short* __restrict__ A1, const short* __restrict__ A2,
               int ksplit, int lda, const short* __restrict__ Bt, int ldb,
               const float* __restrict__ bias, int bias_zmask,
               void* __restrict__ Cout, void* __restrict__ Cz1,
               int ldc, int K, long sA, long sB, long sC)
{
    __shared__ short As[2][64][64];
    __shared__ short Bs[2][64][64];
    const int tid = threadIdx.x;
    const int bn = blockIdx.x * 64, bm = blockIdx.y * 64;
    const long z = blockIdx.z;
    const short* A1z = A1 + z * sA;
    const short* A2z = A2 + z * sA;
    const short* Btz = Bt + z * sB;

    const int lane = tid & 63, w = tid >> 6;
    const int w16 = w * 16;
    const int m0 = (w >> 1) * 32, n0 = (w & 1) * 32;
    const int fr = lane & 15;           // fragment row within 16
    const int fcol = lane >> 4;         // fragment col16 component (0..3)
    const int sl = lane & 7;            // row&7 of every frag row this lane reads
    const int r8 = lane >> 3;           // staging row within 16-row stripe
    const int sw8 = ((lane & 7) ^ ((lane >> 3) & 7)) * 8;  // swizzled src col (shorts)

    f32x4 acc00{}, acc01{}, acc10{}, acc11{};
    const int NS = K >> 6;

    auto stage = [&](int buf, int k0) {
        const short* ab; int ak;
        if (k0 < ksplit) { ab = A1z; ak = k0; }
        else             { ab = A2z; ak = k0 - ksplit; }
        const short* ga = ab + (long)(bm + w16 + r8) * lda + ak + sw8;
        gll16(ga,           &As[buf][w16][0]);
        gll16(ga + 8 * lda, &As[buf][w16 + 8][0]);
        const short* gb = Btz + (long)(bn + w16 + r8) * ldb + k0 + sw8;
        gll16(gb,           &Bs[buf][w16][0]);
        gll16(gb + 8 * ldb, &Bs[buf][w16 + 8][0]);
    };

    stage(0, 0);
    __syncthreads();
    int cur = 0;
    for (int s = 0; s < NS; ++s) {
        if (s + 1 < NS) stage(cur ^ 1, (s + 1) << 6);
#pragma unroll
        for (int ks8 = 0; ks8 < 8; ks8 += 4) {      // ks = 0, 32
            const int sa = ((ks8 + fcol) ^ sl) * 8; // swizzled read col (shorts)
            const short8 a0 = *(const short8*)&As[cur][m0 + fr][sa];
            const short8 a1 = *(const short8*)&As[cur][m0 + 16 + fr][sa];
            const short8 b0 = *(const short8*)&Bs[cur][n0 + fr][sa];
            const short8 b1 = *(const short8*)&Bs[cur][n0 + 16 + fr][sa];
            acc00 = __builtin_amdgcn_mfma_f32_16x16x32_bf16(a0, b0, acc00, 0, 0, 0);
            acc01 = __builtin_amdgcn_mfma_f32_16x16x32_bf16(a0, b1, acc01, 0, 0, 0);
            acc10 = __builtin_amdgcn_mfma_f32_16x16x32_bf16(a1, b0, acc10, 0, 0, 0);
            acc11 = __builtin_amdgcn_mfma_f32_16x16x32_bf16(a1, b1, acc11, 0, 0, 0);
        }
        __syncthreads();
        cur ^= 1;
    }

    const bool doBias = BIAS && ((bias_zmask >> z) & 1);
    float bv[2] = {0.0f, 0.0f};
    if (doBias) {
        bv[0] = bias[bn + n0 + fr];
        bv[1] = bias[bn + n0 + 16 + fr];
    }
    const f32x4 accs[2][2] = {{acc00, acc01}, {acc10, acc11}};
#pragma unroll
    for (int mi = 0; mi < 2; ++mi)
#pragma unroll
        for (int ni = 0; ni < 2; ++ni)
#pragma unroll
            for (int r = 0; r < 4; ++r) {
                const int row = bm + m0 + mi * 16 + ((lane >> 4) << 2) + r;
                const int col = bn + n0 + ni * 16 + fr;
                float v = accs[mi][ni][r];
                if (doBias) v += bv[ni];
                if (LEAKY)  v = leaky(v);
                if (BF16OUT) {
                    short* Ch = (short*)Cout + z * sC;
                    Ch[(long)row * ldc + col] = f2bf(v);
                } else {
                    float* Cf = (Cz1 != nullptr && z == 1)
                              ? (float*)Cz1 : ((float*)Cout + z * sC);
                    Cf[(long)row * ldc + col] = v;
                }
            }
}

// ---------------------------------------------------------------------------
// Fused score + mask + softmax, v4. Block: (b, o-pair), 512 blocks, 256 thr.
// 4 waves = 4 d-quarters; EACH wave computes BOTH o-rows and BOTH i-halves
// per c-load: {w4, av0, av1, c0, c1} = 5 ds_reads per 16 elems (0.31/elem,
// 2.4x less LDS issue than v3, and Cs is read once for both o-rows).
// Partial sums combined via 4KB LDS + 1 barrier; softmax on waves 0/1.
// ---------------------------------------------------------------------------
__global__ __launch_bounds__(256)
void score_softmax4(const float* __restrict__ s_out, const float* __restrict__ s_ctx,
                    const float* __restrict__ score_w, const float* __restrict__ score_b,
                    const int* __restrict__ mask, float* __restrict__ attn_f32,
                    short* __restrict__ attn_b16)
{
    __shared__ float As[2][1032];
    __shared__ float Cs[128][68];
    __shared__ float Wsh[1024];
    __shared__ float Ps[4][2][128];   // [d-quarter][o][i]
    __shared__ int   Msk[128];

    const int b   = blockIdx.x;
    const int o0  = blockIdx.y * 2;
    const int tid = threadIdx.x;
    const int wv  = tid >> 6;         // d-quarter (wave-uniform)
    const int ln  = tid & 63;         // i low half; also owns i+64

    const float* arow = s_out + (long)(b * kO + o0) * kD;
#pragma unroll
    for (int q = 0; q < 2; ++q) {      // 512 float4 = 2 rows x 1024
        const int t  = tid + q * 256;
        const int rr = t >> 8;
        const int c4 = (t & 255) * 4;
        *(float4*)&As[rr][c4] = *(const float4*)&arow[(long)rr * kD + c4];
    }
    *(float4*)&Wsh[tid * 4] = *(const float4*)&score_w[tid * 4];
    if (tid < 128) Msk[tid] = mask[b * kI + tid];

    float a00 = 0.0f, a01 = 0.0f, a10 = 0.0f, a11 = 0.0f;  // [o][ihalf]
    const float* crow = s_ctx + (long)b * kI * kD;
    const int kb = wv * 16;           // this wave's d-slice within each chunk

    for (int dc = 0; dc < kD; dc += 64) {
        __syncthreads();
#pragma unroll
        for (int q = 0; q < 8; ++q) {  // 128x64 floats = 2048 float4
            const int t  = tid + q * 256;
            const int rr = t >> 4;
            const int c4 = (t & 15) * 4;
            *(float4*)&Cs[rr][c4] = *(const float4*)&crow[(long)rr * kD + dc + c4];
        }
        __syncthreads();
#pragma unroll
        for (int kk = 0; kk < 16; kk += 4) {
            const float4 w4  = *(const float4*)&Wsh[dc + kb + kk];
            const float4 av0 = *(const float4*)&As[0][dc + kb + kk];  // broadcast
            const float4 av1 = *(const float4*)&As[1][dc + kb + kk];  // broadcast
            const float4 c0  = *(const float4*)&Cs[ln][kb + kk];
            const float4 c1  = *(const float4*)&Cs[ln + 64][kb + kk];
            a00 = fmaf(leaky(av0.x + c0.x), w4.x, a00);
            a00 = fmaf(leaky(av0.y + c0.y), w4.y, a00);
            a00 = fmaf(leaky(av0.z + c0.z), w4.z, a00);
            a00 = fmaf(leaky(av0.w + c0.w), w4.w, a00);
            a01 = fmaf(leaky(av0.x + c1.x), w4.x, a01);
            a01 = fmaf(leaky(av0.y + c1.y), w4.y, a01);
            a01 = fmaf(leaky(av0.z + c1.z), w4.z, a01);
            a01 = fmaf(leaky(av0.w + c1.w), w4.w, a01);
            a10 = fmaf(leaky(av1.x + c0.x), w4.x, a10);
            a10 = fmaf(leaky(av1.y + c0.y), w4.y, a10);
            a10 = fmaf(leaky(av1.z + c0.z), w4.z, a10);
            a10 = fmaf(leaky(av1.w + c0.w), w4.w, a10);
            a11 = fmaf(leaky(av1.x + c1.x), w4.x, a11);
            a11 = fmaf(leaky(av1.y + c1.y), w4.y, a11);
            a11 = fmaf(leaky(av1.z + c1.z), w4.z, a11);
            a11 = fmaf(leaky(av1.w + c1.w), w4.w, a11);
        }
    }

    Ps[wv][0][ln]      = a00;
    Ps[wv][0][ln + 64] = a01;
    Ps[wv][1][ln]      = a10;
    Ps[wv][1][ln + 64] = a11;
    __syncthreads();

    if (wv < 2) {
        const int ow = wv;            // o-row handled by this wave
        const float negInf = -__builtin_huge_valf();
        const float sb = score_b[0];
        float s0 = Ps[0][ow][ln]      + Ps[1][ow][ln]
                 + Ps[2][ow][ln]      + Ps[3][ow][ln]      + sb;
        float s1 = Ps[0][ow][ln + 64] + Ps[1][ow][ln + 64]
                 + Ps[2][ow][ln + 64] + Ps[3][ow][ln + 64] + sb;
        if (Msk[ln]      != 0) s0 = negInf;
        if (Msk[ln + 64] != 0) s1 = negInf;

        float m = fmaxf(s0, s1);
#pragma unroll
        for (int d = 1; d < 64; d <<= 1) m = fmaxf(m, __shfl_xor(m, d, 64));
        const float e0 = __expf(s0 - m);
        const float e1 = __expf(s1 - m);
        float sum = e0 + e1;
#pragma unroll
        for (int d = 1; d < 64; d <<= 1) sum += __shfl_xor(sum, d, 64);
        const float inv = 1.0f / sum;

        const long rowoff = (long)(b * kO + o0 + ow) * kI;
        float* ro = attn_f32 + rowoff;
        short* rh = attn_b16 + rowoff;
        const float p0 = e0 * inv, p1 = e1 * inv;
        ro[ln]      = p0;
        ro[ln + 64] = p1;
        rh[ln]      = f2bf(p0);
        rh[ln + 64] = f2bf(p1);
    }
}

} // namespace

extern "C" void kernel_launch(void* const* d_in, const int* in_sizes, int n_in,
                              void* d_out, int out_size, void* d_ws, size_t ws_size,
                              hipStream_t stream)
{
    const float* output  = (const float*)d_in[0];   // [B,O,D]
    const float* context = (const float*)d_in[1];   // [B,I,D]
    const int*   mask    = (const int*)d_in[2];     // [B,I]
    const float* w_out_w = (const float*)d_in[3];   // [D,D]
    const float* w_ctx_w = (const float*)d_in[4];   // [D,D]
    const float* w_b     = (const float*)d_in[5];   // [D]
    const float* score_w = (const float*)d_in[6];   // [D]
    const float* score_b = (const float*)d_in[7];   // scalar
    const float* lin_w   = (const float*)d_in[8];   // [2D,D]
    const float* lin_b   = (const float*)d_in[9];   // [D]

    float* out_main = (float*)d_out;                 // [B,O,D]
    float* out_attn = out_main + kOutAttnOff;        // [B,O,I]
    float* s_out    = out_main;                      // overlay: dead before step 5

    char* wp = (char*)d_ws;
    float* s_ctx = (float*)wp;  wp += (size_t)4 << 20;   // 4 MB fp32 [B*I][D]
    short* ob16  = (short*)wp;  wp += (size_t)2 << 20;   // output bf16
    short* cb16  = (short*)wp;  wp += (size_t)2 << 20;   // context bf16 (= ob16+1M)
    short* w1t   = (short*)wp;  wp += (size_t)2 << 20;   // w_out_w^T bf16 [N][K]
    short* w2t   = (short*)wp;  wp += (size_t)2 << 20;   // w_ctx_w^T (= w1t+1M)
    short* lint  = (short*)wp;  wp += (size_t)4 << 20;   // lin_w^T bf16 [1024][2048]
    short* ctxt  = (short*)wp;  wp += (size_t)2 << 20;   // context^T bf16 per-b [1024][128]
    short* attn16 = (short*)wp;                          // 256 KB bf16 attn
    short* t16 = (short*)s_ctx;                          // overlay: s_ctx dead after score

    const dim3 blk(256);

    // 0) all conversions (straight + transposes) in one launch
    hipLaunchKernelGGL(conv_all, dim3(2304), blk, 0, stream,
        output, context, w_out_w, w_ctx_w, lin_w,
        ob16, cb16, w1t, w2t, lint, ctxt);

    // 1+2) fused: z=0: s_out = output @ w_out_w + w_b ; z=1: s_ctx = context @ w_ctx_w
    hipLaunchKernelGGL((gemm_mfma<true, false, false>), dim3(16, 16, 2), blk, 0, stream,
        ob16, ob16, 1024, 1024, w1t, 1024, w_b, /*zmask*/1,
        (void*)s_out, (void*)s_ctx, 1024, 1024, (long)1 << 20, (long)1 << 20, 0L);

    // 3) attn = softmax(mask(leaky(s_out + s_ctx) . score_w + score_b))
    hipLaunchKernelGGL(score_softmax4, dim3(8, 64, 1), blk, 0, stream,
        s_out, s_ctx, score_w, score_b, mask, out_attn, attn16);

    // 4) t = attn @ context  (batched over b, bf16 out)
    hipLaunchKernelGGL((gemm_mfma<false, false, true>), dim3(16, 2, 8), blk, 0, stream,
        attn16, attn16, 128, 128, ctxt, 128, nullptr, 0,
        (void*)t16, nullptr, 1024, 128,
        (long)kO * kI, (long)kI * kD, (long)kO * kD);

    // 5) out = leaky([t | output] @ lin_w + lin_b)
    hipLaunchKernelGGL((gemm_mfma<true, true, false>), dim3(16, 16, 1), blk, 0, stream,
        t16, ob16, 1024, 1024, lint, 2048, lin_b, /*zmask*/1,
        (void*)out_main, nullptr, 1024, 2048, 0L, 0L, 0L);
}

// Round 5
// 68.550 us; speedup vs baseline: 1.6232x; 1.1412x over previous
//
#include <hip/hip_runtime.h>

namespace {

constexpr int kB = 8, kO = 128, kI = 128, kD = 1024;
constexpr long kOutAttnOff = (long)kB * kO * kD;   // 1,048,576 floats

typedef __attribute__((ext_vector_type(8))) short short8;  // 8 bf16 = 4 VGPR
typedef __attribute__((ext_vector_type(4))) float f32x4;

__device__ __forceinline__ float leaky(float x) { return fmaxf(x, 0.01f * x); }

// fp32 -> bf16 round-to-nearest-even
__device__ __forceinline__ short f2bf(float f) {
    unsigned u = __builtin_bit_cast(unsigned, f);
    u += 0x7FFFu + ((u >> 16) & 1u);
    return (short)(u >> 16);
}

// async global->LDS, 16B per lane. LDS dest = wave-uniform base + lane*16.
__device__ __forceinline__ void gll16(const void* g, void* l) {
    __builtin_amdgcn_global_load_lds(
        (const __attribute__((address_space(1))) int*)g,
        (__attribute__((address_space(3))) int*)l, 16, 0, 0);
}

// ---------------------------------------------------------------------------
// All input conversions in ONE kernel.
//   blocks [0,1024):   straight fp32->bf16: output (512) then context (512)
//   blocks [1024,2048): 64x64 transpose+convert tiles:
//     w_out_w (256), w_ctx_w (256), lin_w (512)
// ---------------------------------------------------------------------------
__global__ __launch_bounds__(256)
void conv_all(const float* __restrict__ output, const float* __restrict__ context,
              const float* __restrict__ w1, const float* __restrict__ w2,
              const float* __restrict__ lin,
              short* __restrict__ ob16, short* __restrict__ cb16,
              short* __restrict__ w1t, short* __restrict__ w2t,
              short* __restrict__ lint)
{
    __shared__ float T[64][68];
    const int bid = blockIdx.x, tid = threadIdx.x;

    if (bid < 1024) {                       // straight convert, 8 floats/thread
        const int idx = bid * 256 + tid;
        const float* src; short* dst; int i;
        if (idx < (1 << 17)) { src = output;  dst = ob16; i = idx; }
        else                 { src = context; dst = cb16; i = idx - (1 << 17); }
        const float4* s4 = (const float4*)src + (long)i * 2;
        const float4 v0 = s4[0], v1 = s4[1];
        short8 r;
        r[0] = f2bf(v0.x); r[1] = f2bf(v0.y); r[2] = f2bf(v0.z); r[3] = f2bf(v0.w);
        r[4] = f2bf(v1.x); r[5] = f2bf(v1.y); r[6] = f2bf(v1.z); r[7] = f2bf(v1.w);
        *(short8*)(dst + (long)i * 8) = r;
        return;
    }

    const int tb = bid - 1024;
    const float* src; short* dst; long C, R; int t2;
    if (tb < 256)      { src = w1;  dst = w1t;  R = 1024; C = 1024; t2 = tb; }
    else if (tb < 512) { src = w2;  dst = w2t;  R = 1024; C = 1024; t2 = tb - 256; }
    else               { src = lin; dst = lint; R = 2048; C = 1024; t2 = tb - 512; }
    const int tr = t2 >> 4, tc = t2 & 15;
    const int r = tid >> 2, q = tid & 3;

    const float* s = src + (long)(tr * 64 + r) * C + tc * 64 + q * 16;
    const float4 a0 = ((const float4*)s)[0];
    const float4 a1 = ((const float4*)s)[1];
    const float4 a2 = ((const float4*)s)[2];
    const float4 a3 = ((const float4*)s)[3];
    *(float4*)&T[r][q * 16 + 0]  = a0;
    *(float4*)&T[r][q * 16 + 4]  = a1;
    *(float4*)&T[r][q * 16 + 8]  = a2;
    *(float4*)&T[r][q * 16 + 12] = a3;
    __syncthreads();

    short8 o0, o1;
#pragma unroll
    for (int j = 0; j < 8; ++j)  o0[j] = f2bf(T[q * 16 + j][r]);
#pragma unroll
    for (int j = 0; j < 8; ++j)  o1[j] = f2bf(T[q * 16 + 8 + j][r]);
    short* dp = dst + (long)(tc * 64 + r) * R + tr * 64 + q * 16;
    *(short8*)dp       = o0;
    *((short8*)dp + 1) = o1;
}

// ---------------------------------------------------------------------------
// Fused independent-GEMM job table, ONE launch, 512 blocks (2/CU).
// Tile 64x128, BK=64, K=1024 (16 steps), 4 waves, wave = 32x64 (acc 2x4).
// Double-buffered LDS via global_load_lds w/ XOR chunk swizzle (both sides).
//   job0 (t<128):   s_out  = ob16 @ w1t^T + w_b          (fp32)
//   job1 (t<256):   s_ctx  = cb16 @ w2t^T                (fp32)
//   job2 (t<384):   outlin = ob16 @ lin_bot + lin_b      (fp32)
//   job3 (t<512):   ctxlin[b] = lin_top^T @ ctx[b]^T     (bf16, [1024][128])
// ---------------------------------------------------------------------------
__global__ __launch_bounds__(256)
void mm_jobs(const short* __restrict__ ob16, const short* __restrict__ cb16,
             const short* __restrict__ w1t, const short* __restrict__ w2t,
             const short* __restrict__ lint,
             const float* __restrict__ w_b, const float* __restrict__ lin_b,
             float* __restrict__ s_out, float* __restrict__ s_ctx,
             float* __restrict__ outlin, short* __restrict__ ctxlin)
{
    __shared__ short As[2][64][64];
    __shared__ short Bs[2][128][64];
    const int tid = threadIdx.x;
    const int t = blockIdx.x;
    const int lane = tid & 63, w = tid >> 6;

    const short *Ap, *Bp;
    int lda, ldb, bm, bn, ldc;
    const float* bias = nullptr;
    float* Cf = nullptr;
    short* Ch = nullptr;

    if (t < 384) {
        const int job = t >> 7, jt = t & 127;
        bm = (jt >> 3) * 64; bn = (jt & 7) * 128;
        lda = 1024; ldc = 1024;
        if (job == 0)      { Ap = ob16; Bp = w1t;         ldb = 1024; bias = w_b;   Cf = s_out;  }
        else if (job == 1) { Ap = cb16; Bp = w2t;         ldb = 1024;               Cf = s_ctx;  }
        else               { Ap = ob16; Bp = lint + 1024; ldb = 2048; bias = lin_b; Cf = outlin; }
    } else {
        const int tt = t - 384, bz = tt >> 4, tw = tt & 15;
        bm = tw * 64; bn = 0;
        Ap = lint; lda = 2048;
        Bp = cb16 + (long)bz * (kI * kD); ldb = 1024;
        Ch = ctxlin + (long)bz * (kD * kI); ldc = 128;
    }

    const int m0 = (w >> 1) * 32, n0 = (w & 1) * 64;
    const int fr = lane & 15, fcol = lane >> 4, sl = lane & 7;
    const int r8 = lane >> 3;
    const int sw8 = ((lane & 7) ^ r8) * 8;   // swizzled source col (shorts)
    const int w16 = w * 16, w32 = w * 32;

    f32x4 acc[2][4] = {};

    auto stage = [&](int buf, int k0) {
        const short* ga = Ap + (long)(bm + w16 + r8) * lda + k0 + sw8;
        gll16(ga,                 &As[buf][w16][0]);
        gll16(ga + 8 * (long)lda, &As[buf][w16 + 8][0]);
        const short* gb = Bp + (long)(bn + w32 + r8) * ldb + k0 + sw8;
        gll16(gb,                  &Bs[buf][w32][0]);
        gll16(gb + 8 * (long)ldb,  &Bs[buf][w32 + 8][0]);
        gll16(gb + 16 * (long)ldb, &Bs[buf][w32 + 16][0]);
        gll16(gb + 24 * (long)ldb, &Bs[buf][w32 + 24][0]);
    };

    stage(0, 0);
    __syncthreads();
    int cur = 0;
    for (int s = 0; s < 16; ++s) {
        if (s < 15) stage(cur ^ 1, (s + 1) << 6);
#pragma unroll
        for (int ks8 = 0; ks8 < 8; ks8 += 4) {      // ks = 0, 32
            const int sa = ((ks8 + fcol) ^ sl) * 8; // swizzled read col (shorts)
            short8 a[2], b[4];
#pragma unroll
            for (int mi = 0; mi < 2; ++mi)
                a[mi] = *(const short8*)&As[cur][m0 + mi * 16 + fr][sa];
#pragma unroll
            for (int ni = 0; ni < 4; ++ni)
                b[ni] = *(const short8*)&Bs[cur][n0 + ni * 16 + fr][sa];
#pragma unroll
            for (int mi = 0; mi < 2; ++mi)
#pragma unroll
                for (int ni = 0; ni < 4; ++ni)
                    acc[mi][ni] = __builtin_amdgcn_mfma_f32_16x16x32_bf16(
                        a[mi], b[ni], acc[mi][ni], 0, 0, 0);
        }
        __syncthreads();
        cur ^= 1;
    }

    float bv[4] = {0, 0, 0, 0};
    if (bias) {
#pragma unroll
        for (int ni = 0; ni < 4; ++ni) bv[ni] = bias[bn + n0 + ni * 16 + fr];
    }
#pragma unroll
    for (int mi = 0; mi < 2; ++mi)
#pragma unroll
        for (int ni = 0; ni < 4; ++ni)
#pragma unroll
            for (int r = 0; r < 4; ++r) {
                const int row = bm + m0 + mi * 16 + ((lane >> 4) << 2) + r;
                const int col = bn + n0 + ni * 16 + fr;
                float v = acc[mi][ni][r] + bv[ni];
                if (Ch) Ch[(long)row * ldc + col] = f2bf(v);
                else    Cf[(long)row * ldc + col] = v;
            }
}

// ---------------------------------------------------------------------------
// Fused score + mask + softmax, v5. Block = (b, o-quad): 256 blocks, 256 thr.
// 4 waves = 4 d-quarters; each wave computes 4 o-rows x 128 i on its 16-d
// slice per 64-d chunk -> LDS data ~1B/elem, s_ctx L2 traffic halved.
// Cs chunks double-buffered via global_load_lds (XOR chunk swizzle, both
// sides) so fills overlap compute. Partials via 8KB LDS; softmax 1 wave/o.
// ---------------------------------------------------------------------------
__global__ __launch_bounds__(256)
void score_softmax5(const float* __restrict__ s_out, const float* __restrict__ s_ctx,
                    const float* __restrict__ score_w, const float* __restrict__ score_b,
                    const int* __restrict__ mask, float* __restrict__ attn_f32,
                    short* __restrict__ attn_b16)
{
    __shared__ float As[4][1032];
    __shared__ float Cs[2][128][64];   // chunk-swizzled: [i][ch] = g[i][ch^(i&7)]
    __shared__ float Wsh[1024];
    __shared__ float Ps[4][4][128];    // [d-quarter][o][i]
    __shared__ int   Msk[128];

    const int b   = blockIdx.x;
    const int o0  = blockIdx.y * 4;
    const int tid = threadIdx.x;
    const int wv  = tid >> 6;          // d-quarter (wave-uniform)
    const int ln  = tid & 63;          // i low half; also owns i+64

    const float* arow = s_out + (long)(b * kO + o0) * kD;
#pragma unroll
    for (int q = 0; q < 4; ++q) {      // 4 rows x 1024 = 1024 float4
        const int tq = tid + q * 256;
        const int rr = tq >> 8, c4 = (tq & 255) * 4;
        *(float4*)&As[rr][c4] = *(const float4*)&arow[(long)rr * kD + c4];
    }
    *(float4*)&Wsh[tid * 4] = *(const float4*)&score_w[tid * 4];
    if (tid < 128) Msk[tid] = mask[b * kI + tid];

    const float* crow = s_ctx + (long)b * kI * kD;
    const int srow = wv * 4 + (ln >> 4);            // staging row (+ it*16)
    const int cho  = ((ln & 15) ^ (srow & 7)) * 4;  // pre-swizzled source col

    auto stageCs = [&](int buf, int dc) {
#pragma unroll
        for (int it = 0; it < 8; ++it)
            gll16(crow + (long)(srow + it * 16) * kD + dc + cho,
                  &Cs[buf][wv * 4 + it * 16][0]);
    };

    float a0[4] = {}, a1[4] = {};      // per-o accumulators, i and i+64
    const int kb = wv * 16;            // this wave's d-slice within each chunk

    stageCs(0, 0);
    __syncthreads();
    int buf = 0;
    for (int c = 0; c < 16; ++c) {
        const int dc = c * 64;
        if (c < 15) stageCs(buf ^ 1, dc + 64);
#pragma unroll
        for (int kq = 0; kq < 4; ++kq) {
            const int sc = ((wv * 4 + kq) ^ (ln & 7)) * 4;   // swizzled read
            const float4 c0 = *(const float4*)&Cs[buf][ln][sc];
            const float4 c1 = *(const float4*)&Cs[buf][ln + 64][sc];
            const float4 w4 = *(const float4*)&Wsh[dc + kb + kq * 4];
#pragma unroll
            for (int o = 0; o < 4; ++o) {
                const float4 av = *(const float4*)&As[o][dc + kb + kq * 4];
                a0[o] = fmaf(leaky(av.x + c0.x), w4.x, a0[o]);
                a0[o] = fmaf(leaky(av.y + c0.y), w4.y, a0[o]);
                a0[o] = fmaf(leaky(av.z + c0.z), w4.z, a0[o]);
                a0[o] = fmaf(leaky(av.w + c0.w), w4.w, a0[o]);
                a1[o] = fmaf(leaky(av.x + c1.x), w4.x, a1[o]);
                a1[o] = fmaf(leaky(av.y + c1.y), w4.y, a1[o]);
                a1[o] = fmaf(leaky(av.z + c1.z), w4.z, a1[o]);
                a1[o] = fmaf(leaky(av.w + c1.w), w4.w, a1[o]);
            }
        }
        __syncthreads();               // drains gll16 vmcnt + protects Cs
        buf ^= 1;
    }

#pragma unroll
    for (int o = 0; o < 4; ++o) {
        Ps[wv][o][ln]      = a0[o];
        Ps[wv][o][ln + 64] = a1[o];
    }
    __syncthreads();

    const int ow = wv;                 // wave handles o-row ow
    const float negInf = -__builtin_huge_valf();
    const float sb = score_b[0];
    float s0 = Ps[0][ow][ln]      + Ps[1][ow][ln]
             + Ps[2][ow][ln]      + Ps[3][ow][ln]      + sb;
    float s1 = Ps[0][ow][ln + 64] + Ps[1][ow][ln + 64]
             + Ps[2][ow][ln + 64] + Ps[3][ow][ln + 64] + sb;
    if (Msk[ln]      != 0) s0 = negInf;
    if (Msk[ln + 64] != 0) s1 = negInf;

    float m = fmaxf(s0, s1);
#pragma unroll
    for (int d = 1; d < 64; d <<= 1) m = fmaxf(m, __shfl_xor(m, d, 64));
    const float e0 = __expf(s0 - m);
    const float e1 = __expf(s1 - m);
    float sum = e0 + e1;
#pragma unroll
    for (int d = 1; d < 64; d <<= 1) sum += __shfl_xor(sum, d, 64);
    const float inv = 1.0f / sum;

    const long rowoff = (long)(b * kO + o0 + ow) * kI;
    float* ro = attn_f32 + rowoff;
    short* rh = attn_b16 + rowoff;
    const float p0 = e0 * inv, p1 = e1 * inv;
    ro[ln]      = p0;
    ro[ln + 64] = p1;
    rh[ln]      = f2bf(p0);
    rh[ln + 64] = f2bf(p1);
}

// ---------------------------------------------------------------------------
// Final: out[b] = leaky(attn16[b] @ ctxlin[b]^T + outlin[b-rows]).
// 64x64 tile, K=128 (2 steps), grid (16, 2, 8). lin_b already in outlin.
// ---------------------------------------------------------------------------
__global__ __launch_bounds__(256)
void gemm_final(const short* __restrict__ A, const short* __restrict__ Bt,
                const float* __restrict__ addend, float* __restrict__ C)
{
    __shared__ short As[2][64][64];
    __shared__ short Bs[2][64][64];
    const int tid = threadIdx.x;
    const int bn = blockIdx.x * 64, bm = blockIdx.y * 64;
    const long z = blockIdx.z;
    const short* Az = A + z * (long)(kO * kI);        // attn16 [128][128]
    const short* Bz = Bt + z * (long)(kD * kI);       // ctxlin [1024][128]
    const float* adz = addend + z * (long)(kO * kD);  // outlin rows
    float* Cz = C + z * (long)(kO * kD);

    const int lane = tid & 63, w = tid >> 6;
    const int w16 = w * 16;
    const int m0 = (w >> 1) * 32, n0 = (w & 1) * 32;
    const int fr = lane & 15, fcol = lane >> 4, sl = lane & 7;
    const int r8 = lane >> 3;
    const int sw8 = ((lane & 7) ^ r8) * 8;

    f32x4 acc[2][2] = {};

    auto stage = [&](int buf, int k0) {
        const short* ga = Az + (long)(bm + w16 + r8) * kI + k0 + sw8;
        gll16(ga,          &As[buf][w16][0]);
        gll16(ga + 8 * kI, &As[buf][w16 + 8][0]);
        const short* gb = Bz + (long)(bn + w16 + r8) * kI + k0 + sw8;
        gll16(gb,          &Bs[buf][w16][0]);
        gll16(gb + 8 * kI, &Bs[buf][w16 + 8][0]);
    };

    stage(0, 0);
    __syncthreads();
    int cur = 0;
    for (int s = 0; s < 2; ++s) {
        if (s == 0) stage(1, 64);
#pragma unroll
        for (int ks8 = 0; ks8 < 8; ks8 += 4) {
            const int sa = ((ks8 + fcol) ^ sl) * 8;
            const short8 a0 = *(const short8*)&As[cur][m0 + fr][sa];
            const short8 a1 = *(const short8*)&As[cur][m0 + 16 + fr][sa];
            const short8 b0 = *(const short8*)&Bs[cur][n0 + fr][sa];
            const short8 b1 = *(const short8*)&Bs[cur][n0 + 16 + fr][sa];
            acc[0][0] = __builtin_amdgcn_mfma_f32_16x16x32_bf16(a0, b0, acc[0][0], 0, 0, 0);
            acc[0][1] = __builtin_amdgcn_mfma_f32_16x16x32_bf16(a0, b1, acc[0][1], 0, 0, 0);
            acc[1][0] = __builtin_amdgcn_mfma_f32_16x16x32_bf16(a1, b0, acc[1][0], 0, 0, 0);
            acc[1][1] = __builtin_amdgcn_mfma_f32_16x16x32_bf16(a1, b1, acc[1][1], 0, 0, 0);
        }
        __syncthreads();
        cur ^= 1;
    }

#pragma unroll
    for (int mi = 0; mi < 2; ++mi)
#pragma unroll
        for (int ni = 0; ni < 2; ++ni)
#pragma unroll
            for (int r = 0; r < 4; ++r) {
                const int row = bm + m0 + mi * 16 + ((lane >> 4) << 2) + r;
                const int col = bn + n0 + ni * 16 + fr;
                const float v = acc[mi][ni][r] + adz[(long)row * kD + col];
                Cz[(long)row * kD + col] = leaky(v);
            }
}

} // namespace

extern "C" void kernel_launch(void* const* d_in, const int* in_sizes, int n_in,
                              void* d_out, int out_size, void* d_ws, size_t ws_size,
                              hipStream_t stream)
{
    const float* output  = (const float*)d_in[0];   // [B,O,D]
    const float* context = (const float*)d_in[1];   // [B,I,D]
    const int*   mask    = (const int*)d_in[2];     // [B,I]
    const float* w_out_w = (const float*)d_in[3];   // [D,D]
    const float* w_ctx_w = (const float*)d_in[4];   // [D,D]
    const float* w_b     = (const float*)d_in[5];   // [D]
    const float* score_w = (const float*)d_in[6];   // [D]
    const float* score_b = (const float*)d_in[7];   // scalar
    const float* lin_w   = (const float*)d_in[8];   // [2D,D]
    const float* lin_b   = (const float*)d_in[9];   // [D]

    float* out_main = (float*)d_out;                 // [B,O,D]
    float* out_attn = out_main + kOutAttnOff;        // [B,O,I]
    float* s_out    = out_main;                      // overlay: dead before final

    char* wp = (char*)d_ws;
    float* s_ctx  = (float*)wp;  wp += (size_t)4 << 20;  // fp32 [B*I][D]
    short* ob16   = (short*)wp;  wp += (size_t)2 << 20;  // output bf16
    short* cb16   = (short*)wp;  wp += (size_t)2 << 20;  // context bf16
    short* w1t    = (short*)wp;  wp += (size_t)2 << 20;  // w_out_w^T bf16
    short* w2t    = (short*)wp;  wp += (size_t)2 << 20;  // w_ctx_w^T bf16
    short* lint   = (short*)wp;  wp += (size_t)4 << 20;  // lin_w^T bf16 [1024][2048]
    float* outlin = (float*)wp;  wp += (size_t)4 << 20;  // output@lin_bot+lin_b fp32
    short* ctxlin = (short*)wp;  wp += (size_t)2 << 20;  // (ctx@lin_top)^T bf16 [b][1024][128]
    short* attn16 = (short*)wp;                          // 256 KB bf16 attn

    const dim3 blk(256);

    // 1) all conversions
    hipLaunchKernelGGL(conv_all, dim3(2048), blk, 0, stream,
        output, context, w_out_w, w_ctx_w, lin_w, ob16, cb16, w1t, w2t, lint);

    // 2) all input-independent GEMMs in one 512-block launch
    hipLaunchKernelGGL(mm_jobs, dim3(512), blk, 0, stream,
        ob16, cb16, w1t, w2t, lint, w_b, lin_b, s_out, s_ctx, outlin, ctxlin);

    // 3) attn = softmax(mask(leaky(s_out + s_ctx) . score_w + score_b))
    hipLaunchKernelGGL(score_softmax5, dim3(8, 32), blk, 0, stream,
        s_out, s_ctx, score_w, score_b, mask, out_attn, attn16);

    // 4) out = leaky(attn @ ctxlin^T + outlin)
    hipLaunchKernelGGL(gemm_final, dim3(16, 2, 8), blk, 0, stream,
        attn16, ctxlin, outlin, out_main);
}